// Round 8
// baseline (327.743 us; speedup 1.0000x reference)
//
#include <hip/hip_runtime.h>

typedef _Float16 f16;
typedef __attribute__((ext_vector_type(2))) __fp16 h16x2;
typedef __attribute__((ext_vector_type(4))) _Float16 f16x4;
typedef __attribute__((ext_vector_type(8))) _Float16 f16x8;
typedef __attribute__((ext_vector_type(4))) float f32x4;
typedef __attribute__((ext_vector_type(16))) float f32x16;

#define B_ 2
#define S_ 2048
#define DMODEL 768
#define H_ 12
#define HS 64
#define NB_ 16
#define QKV_LD 2304   // q,k,v concatenated columns

#define ZERO16 {0.f,0.f,0.f,0.f,0.f,0.f,0.f,0.f,0.f,0.f,0.f,0.f,0.f,0.f,0.f,0.f}

// async global->LDS 16B: LDS dest = wave-uniform base + lane*16
__device__ __forceinline__ void gload16(const f16* g, f16* lds) {
    __builtin_amdgcn_global_load_lds((const __attribute__((address_space(1))) void*)g,
                                     (__attribute__((address_space(3))) void*)lds, 16, 0, 0);
}

// ---------------- fused prep: casts + bias table ----------------
// grid 5568: [0,3072) x | [3072,4800) Wq|Wk|Wv | [4800,5376) Wo | [5376,5568) bias
__global__ __launch_bounds__(256) void prep_kernel(const float* __restrict__ x,
                                                   const float* __restrict__ Wq,
                                                   const float* __restrict__ Wk,
                                                   const float* __restrict__ Wv,
                                                   const float* __restrict__ Wo,
                                                   const float* __restrict__ bw,
                                                   const float* __restrict__ bf,
                                                   f16* __restrict__ xb,
                                                   f16* __restrict__ wqkv16,
                                                   f16* __restrict__ wo16,
                                                   float* __restrict__ biasTab) {
    int bid = blockIdx.x;
    int t = threadIdx.x;
    if (bid < 5376) {
        const float* src;
        f16* dst;
        float scale = 1.0f;
        int i;
        if (bid < 3072) {            // x: 786432 float4
            i = bid * 256 + t; src = x; dst = xb;
        } else if (bid < 4800) {     // Wq|Wk|Wv: 3 x 147456 float4 -> contiguous wqkv16
            i = (bid - 3072) * 256 + t;
            dst = wqkv16;
            if (i < 147456)      { src = Wq; scale = 0.18033688011112f; }   // (1/8)*log2e
            else if (i < 294912) { src = Wk - 147456 * 4; }
            else                 { src = Wv - 294912 * 4; }
        } else {                     // Wo: 147456 float4
            i = (bid - 4800) * 256 + t; src = Wo; dst = wo16;
        }
        f32x4 v = reinterpret_cast<const f32x4*>(src)[i];
        union { f16 h[4]; unsigned long long u; } o;
        o.h[0] = (f16)(v.x * scale);
        o.h[1] = (f16)(v.y * scale);
        o.h[2] = (f16)(v.z * scale);
        o.h[3] = (f16)(v.w * scale);
        reinterpret_cast<unsigned long long*>(dst)[i] = o.u;
    } else {                         // bias table, log2 domain
        int idx = (bid - 5376) * 256 + t;
        if (idx >= H_ * 4095) return;
        int h = idx / 4095, d = idx % 4095;
        int rel = min(1000, max(-1000, d - 2047));
        int r = rel + 1000;
        float s = 0.f;
#pragma unroll
        for (int tt = 0; tt < NB_; ++tt) s += bf[r * NB_ + tt] * bw[h * NB_ + tt];
        biasTab[h * 4095 + d] = s * 1.44269504088896f;
    }
}

// ---------------- V transpose: vt[(b*H+h)*64 + v][token] = V[b][token][h*64+v] ----------------
__global__ __launch_bounds__(256) void vtrans_kernel(const f16* __restrict__ qkv,
                                                     f16* __restrict__ vt) {
    __shared__ f16 tile[64][72];
    int blk = blockIdx.x;            // (b*H+h)*32 + tb
    int tb = blk & 31;
    int bh = blk >> 5;
    int b = bh / H_;
    int tok0 = tb << 6;
    int t = threadIdx.x;
    const f16* src = qkv + (size_t)b * S_ * QKV_LD + 1536 + (bh - b * H_) * 64;
#pragma unroll
    for (int j = 0; j < 2; ++j) {
        int u = t + (j << 8);
        int r = u >> 3, c = (u & 7) << 3;
        *reinterpret_cast<f16x8*>(&tile[r][c]) =
            *reinterpret_cast<const f16x8*>(src + (size_t)(tok0 + r) * QKV_LD + c);
    }
    __syncthreads();
    f16* dst = vt + (size_t)bh * 64 * S_ + tok0;
#pragma unroll
    for (int j = 0; j < 2; ++j) {
        int u = t + (j << 8);
        int v = u >> 3, tc = (u & 7) << 3;
        union { f16 h8[8]; f16x8 v8; } o;
#pragma unroll
        for (int i = 0; i < 8; ++i) o.h8[i] = tile[tc + i][v];
        *reinterpret_cast<f16x8*>(&dst[(size_t)v * S_ + tc]) = o.v8;
    }
}

// ---------------- NT GEMM via global_load_lds, source-pre-swizzled chunks ----------------
template <typename OutT>
__global__ __launch_bounds__(256) void gemm_nt(const f16* __restrict__ A,
                                               const f16* __restrict__ Bm,
                                               OutT* __restrict__ C,
                                               int M, int N, int K, float alpha) {
    __shared__ __align__(16) f16 As[128 * 32];
    __shared__ __align__(16) f16 Bs[128 * 32];
    const int tiles_n = N >> 7;
    int tm = blockIdx.x / tiles_n, tn = blockIdx.x % tiles_n;
    int m0 = tm << 7, n0 = tn << 7;
    int t = threadIdx.x;
    int w = t >> 6, l = t & 63;
    int wr = w >> 1, wc = w & 1;
    int fr = l & 15, hi = l >> 4;
    f32x4 acc[4][4] = {};

    for (int k0 = 0; k0 < K; k0 += 32) {
#pragma unroll
        for (int j = 0; j < 2; ++j) {
            int u = t + (j << 8);
            int row = u >> 2, ch = u & 3;
            int gcol = k0 + ((ch ^ (row & 3)) << 3);
            gload16(&A[(size_t)(m0 + row) * K + gcol], As + (w << 9) + (j << 11));
            gload16(&Bm[(size_t)(n0 + row) * K + gcol], Bs + (w << 9) + (j << 11));
        }
        __syncthreads();
        f16x8 af[4], bfv[4];
#pragma unroll
        for (int m = 0; m < 4; ++m) {
            int row = wr * 64 + m * 16 + fr;
            af[m] = *reinterpret_cast<const f16x8*>(&As[row * 32 + ((hi ^ (fr & 3)) << 3)]);
        }
#pragma unroll
        for (int n = 0; n < 4; ++n) {
            int row = wc * 64 + n * 16 + fr;
            bfv[n] = *reinterpret_cast<const f16x8*>(&Bs[row * 32 + ((hi ^ (fr & 3)) << 3)]);
        }
#pragma unroll
        for (int m = 0; m < 4; ++m)
#pragma unroll
            for (int n = 0; n < 4; ++n)
                acc[m][n] = __builtin_amdgcn_mfma_f32_16x16x32_f16(af[m], bfv[n], acc[m][n], 0, 0, 0);
        __syncthreads();
    }
    int cc = l & 15, cr = (l >> 4) << 2;
#pragma unroll
    for (int m = 0; m < 4; ++m)
#pragma unroll
        for (int n = 0; n < 4; ++n)
#pragma unroll
            for (int j = 0; j < 4; ++j) {
                int rg = m0 + wr * 64 + m * 16 + cr + j;
                int cg = n0 + wc * 64 + n * 16 + cc;
                C[(size_t)rg * N + cg] = (OutT)(acc[m][n][j] * alpha);
            }
}

// ---------------- attention v6: swapped QK^T (lane-local k), in-register PV B ----------------
// Block: 256 threads = 4 waves (wq,wk). mfma(K,Q) -> D[k][q], lane = q. Each lane owns one
// q-row: scalar lsum, float4 attn stores, PV B-fragment assembled in-register via
// cvt_pkrtz + shfl_xor(32). O^T accumulated per wave; cross-wk LDS reduce at end.
__global__ __launch_bounds__(256, 4) void attn_kernel(const f16* __restrict__ qp,
                                                      const f16* __restrict__ kp,
                                                      const f16* __restrict__ vt,
                                                      const float* __restrict__ biasTab,
                                                      float* __restrict__ attn_out,
                                                      f16* __restrict__ ctx_out) {
    __shared__ __align__(16) union {
        f16 ks1[128 * 64];                               // pass 1: 16384 B
        struct { f16 ks[64 * 64]; f16 vs[64 * 64]; } p2; // pass 2: 16384 B
        float red[4096];                                 // epilogue: 16384 B
    } ar;
    __shared__ float bias_l[2112];                       // 8448 B
    __shared__ float red_l[64][2];

    // XCD-chunked swizzle: 768 = 8 * 96
    int orig = blockIdx.x;
    int blk = (orig & 7) * 96 + (orig >> 3);
    int qt = blk & 31;
    int bh = blk >> 5;
    int h = bh % H_;
    int b = bh / H_;
    int q0 = qt << 6;

    int t = threadIdx.x;
    int w = t >> 6, l = t & 63;
    int wq = w >> 1, wk = w & 1;
    int ql = l & 31;
    int hi = l >> 5;
    int hi8 = hi << 3;

    const size_t rowbase = (size_t)b * S_ * QKV_LD + (size_t)h * HS;
    const f16* vbase = vt + (size_t)bh * HS * S_;

    // Q fragments (B-operand now): lane = q col = wq*32+ql, elements c = ci*16+hi8+[0,8)
    f16x8 qf[4];
    {
        const f16* qrow = qp + rowbase + (size_t)(q0 + wq * 32 + ql) * QKV_LD + hi8;
#pragma unroll
        for (int ci = 0; ci < 4; ++ci) qf[ci] = *reinterpret_cast<const f16x8*>(qrow + ci * 16);
    }

    // stage bias slice: bias_l[i] = biasTab[h][i + 1984 - q0]; i = k - qrow + 63 in [0,2110]
    {
        const float* bt = biasTab + h * 4095 + (1984 - q0);
        for (int i = t; i < 2111; i += 256) bias_l[i] = bt[i];
    }

    // ---------------- pass 1: per-lane scalar row sum ----------------
    float lsum = 0.f;
    for (int kb0 = 0; kb0 < S_; kb0 += 128) {
#pragma unroll
        for (int j = 0; j < 4; ++j) {
            int u = t + (j << 8);
            int row = u >> 3, ch = u & 7;
            gload16(kp + rowbase + (size_t)(kb0 + row) * QKV_LD + ((ch ^ (row & 7)) << 3),
                    ar.ks1 + (w << 9) + (j << 11));
        }
        __syncthreads();
        const float* bl = bias_l + (kb0 + wk * 32 + 63 + (hi << 2) - wq * 32 - ql);
#pragma unroll
        for (int half = 0; half < 2; ++half) {
            int arow = half * 64 + wk * 32 + ql;
            f32x16 s = ZERO16;
#pragma unroll
            for (int ci = 0; ci < 4; ++ci) {
                f16x8 kf = *reinterpret_cast<const f16x8*>(
                    &ar.ks1[arow * 64 + (((ci * 2 + hi) ^ (arow & 7)) << 3)]);
                s = __builtin_amdgcn_mfma_f32_32x32x16_f16(kf, qf[ci], s, 0, 0, 0);
            }
            const float* blh = bl + half * 64;
#pragma unroll
            for (int r = 0; r < 16; ++r)
                lsum += __builtin_amdgcn_exp2f(s[r] + blh[((r >> 2) << 3) + (r & 3)]);
        }
        __syncthreads();
    }
    lsum += __shfl_xor(lsum, 32);
    if (hi == 0) red_l[wq * 32 + ql][wk] = lsum;
    __syncthreads();
    const float lreg = 1.0f / (red_l[wq * 32 + ql][0] + red_l[wq * 32 + ql][1]);

    // ---------------- pass 2: recompute, float4 attn stores, in-register PV ----------------
    f32x16 oacc0 = ZERO16, oacc1 = ZERO16;
    float* arow_out = attn_out + (((size_t)b * H_ + h) * S_ + q0) * S_
                    + (size_t)(wq * 32 + ql) * S_;

    for (int kb0 = 0; kb0 < S_; kb0 += 64) {
#pragma unroll
        for (int j = 0; j < 2; ++j) {
            int u = t + (j << 8);
            int row = u >> 3, ch = u & 7;
            int sw = ((ch ^ (row & 7)) << 3);
            gload16(kp + rowbase + (size_t)(kb0 + row) * QKV_LD + sw,
                    ar.p2.ks + (w << 9) + (j << 11));
            gload16(vbase + (size_t)row * S_ + kb0 + sw,
                    ar.p2.vs + (w << 9) + (j << 11));
        }
        __syncthreads();
        int arow = wk * 32 + ql;
        f32x16 s = ZERO16;
#pragma unroll
        for (int ci = 0; ci < 4; ++ci) {
            f16x8 kf = *reinterpret_cast<const f16x8*>(
                &ar.p2.ks[arow * 64 + (((ci * 2 + hi) ^ (arow & 7)) << 3)]);
            s = __builtin_amdgcn_mfma_f32_32x32x16_f16(kf, qf[ci], s, 0, 0, 0);
        }
        const float* bl = bias_l + (kb0 + wk * 32 + 63 + (hi << 2) - wq * 32 - ql);
        unsigned w2[8];
#pragma unroll
        for (int r4 = 0; r4 < 4; ++r4) {
            float p0 = __builtin_amdgcn_exp2f(s[4 * r4 + 0] + bl[8 * r4 + 0]) * lreg;
            float p1 = __builtin_amdgcn_exp2f(s[4 * r4 + 1] + bl[8 * r4 + 1]) * lreg;
            float p2 = __builtin_amdgcn_exp2f(s[4 * r4 + 2] + bl[8 * r4 + 2]) * lreg;
            float p3 = __builtin_amdgcn_exp2f(s[4 * r4 + 3] + bl[8 * r4 + 3]) * lreg;
            f32x4 st = {p0, p1, p2, p3};
            __builtin_nontemporal_store(st, reinterpret_cast<f32x4*>(
                arow_out + kb0 + wk * 32 + 8 * r4 + (hi << 2)));
            union { h16x2 h; unsigned u; } c0, c1;
            c0.h = __builtin_amdgcn_cvt_pkrtz(p0, p1);
            c1.h = __builtin_amdgcn_cvt_pkrtz(p2, p3);
            w2[2 * r4] = c0.u;
            w2[2 * r4 + 1] = c1.u;
        }
        unsigned sw2[8];
#pragma unroll
        for (int i = 0; i < 8; ++i) sw2[i] = __shfl_xor(w2[i], 32);
        // PV: O^T[v][q] += V^T[v][k] * P[k][q], contraction over this wave's 32 k
#pragma unroll
        for (int vh = 0; vh < 2; ++vh) {
            int vrow = vh * 32 + ql;
#pragma unroll
            for (int ci = 0; ci < 2; ++ci) {
                f16x8 vf = *reinterpret_cast<const f16x8*>(
                    &ar.p2.vs[vrow * 64 + (((wk * 4 + ci * 2 + hi) ^ (vrow & 7)) << 3)]);
                int bb = ci * 4 + (hi << 1);
                union { unsigned u[4]; f16x8 v; } pf;
                pf.u[0] = hi ? sw2[bb] : w2[bb];
                pf.u[1] = hi ? sw2[bb + 1] : w2[bb + 1];
                pf.u[2] = hi ? w2[bb] : sw2[bb];
                pf.u[3] = hi ? w2[bb + 1] : sw2[bb + 1];
                if (vh == 0)
                    oacc0 = __builtin_amdgcn_mfma_f32_32x32x16_f16(vf, pf.v, oacc0, 0, 0, 0);
                else
                    oacc1 = __builtin_amdgcn_mfma_f32_32x32x16_f16(vf, pf.v, oacc1, 0, 0, 0);
            }
        }
        __syncthreads();
    }

    // ---------------- epilogue: cross-wk reduce O^T, write ctx ----------------
    if (wk == 1) {
#pragma unroll
        for (int r = 0; r < 16; ++r) {
            int v = (r & 3) + ((r >> 2) << 3) + (hi << 2);
            ar.red[wq * 2048 + v * 32 + ql] = oacc0[r];
            ar.red[wq * 2048 + (v + 32) * 32 + ql] = oacc1[r];
        }
    }
    __syncthreads();
    if (wk == 0) {
        f16* cbase = ctx_out + ((size_t)b * S_ + q0 + wq * 32 + ql) * DMODEL + h * HS;
#pragma unroll
        for (int vh = 0; vh < 2; ++vh) {
#pragma unroll
            for (int r4 = 0; r4 < 4; ++r4) {
                f16x4 o4;
#pragma unroll
                for (int rr = 0; rr < 4; ++rr) {
                    int r = 4 * r4 + rr;
                    int v = vh * 32 + rr + (r4 << 3) + (hi << 2);
                    float own = (vh == 0) ? oacc0[r] : oacc1[r];
                    o4[rr] = (f16)(own + ar.red[wq * 2048 + v * 32 + ql]);
                }
                *reinterpret_cast<f16x4*>(cbase + vh * 32 + (r4 << 3) + (hi << 2)) = o4;
            }
        }
    }
}

// ---------------- launch ----------------
extern "C" void kernel_launch(void* const* d_in, const int* in_sizes, int n_in,
                              void* d_out, int out_size, void* d_ws, size_t ws_size,
                              hipStream_t stream) {
    const float* x     = (const float*)d_in[0];
    const float* Wq    = (const float*)d_in[1];
    const float* Wk    = (const float*)d_in[2];
    const float* Wv    = (const float*)d_in[3];
    const float* Wo    = (const float*)d_in[4];
    const float* bw    = (const float*)d_in[5];
    const float* bfeat = (const float*)d_in[6];

    char* ws = (char*)d_ws;
    f16*   xb      = (f16*)(ws + 0);           // 4096x768      6,291,456 B (reused as vt after QKV GEMM)
    f16*   vt      = (f16*)(ws + 0);           // 24x64x2048    6,291,456 B
    f16*   qkv     = (f16*)(ws + 6291456);     // 4096x2304    18,874,368 B
    f16*   ctx     = (f16*)(ws + 25165824);    // 4096x768      6,291,456 B
    f16*   wqkv16  = (f16*)(ws + 31457280);    // 2304x768      3,538,944 B
    f16*   wo16    = (f16*)(ws + 34996224);    // 768x768       1,179,648 B
    float* biasTab = (float*)(ws + 36175872);  // 12x4095         196,560 B

    float* out0 = (float*)d_out;
    float* attn = out0 + (size_t)B_ * S_ * DMODEL;

    prep_kernel<<<5568, 256, 0, stream>>>(x, Wq, Wk, Wv, Wo, bw, bfeat,
                                          xb, wqkv16, wo16, biasTab);

    gemm_nt<f16><<<32 * 18, 256, 0, stream>>>(xb, wqkv16, qkv, 4096, QKV_LD, 768, 1.0f);

    vtrans_kernel<<<768, 256, 0, stream>>>(qkv, vt);

    attn_kernel<<<B_ * H_ * (S_ / 64), 256, 0, stream>>>(
        qkv + 0, qkv + 768, vt, biasTab, attn, ctx);

    gemm_nt<float><<<32 * 6, 256, 0, stream>>>(ctx, wo16, out0, 4096, DMODEL, 768, 1.0f);
}

// Round 9
// 214.713 us; speedup vs baseline: 1.5264x; 1.5264x over previous
//
#include <hip/hip_runtime.h>

typedef _Float16 f16;
typedef __attribute__((ext_vector_type(4))) _Float16 f16x4;
typedef __attribute__((ext_vector_type(8))) _Float16 f16x8;
typedef __attribute__((ext_vector_type(4))) float f32x4;
typedef __attribute__((ext_vector_type(16))) float f32x16;

#define B_ 2
#define S_ 2048
#define DMODEL 768
#define H_ 12
#define HS 64
#define NB_ 16
#define QKV_LD 2304   // q,k,v concatenated columns

#define ZERO16 {0.f,0.f,0.f,0.f,0.f,0.f,0.f,0.f,0.f,0.f,0.f,0.f,0.f,0.f,0.f,0.f}

// async global->LDS 16B: LDS dest = wave-uniform base + lane*16
__device__ __forceinline__ void gload16(const f16* g, f16* lds) {
    __builtin_amdgcn_global_load_lds((const __attribute__((address_space(1))) void*)g,
                                     (__attribute__((address_space(3))) void*)lds, 16, 0, 0);
}

// ---------------- fused prep: casts + bias table ----------------
// grid 5568: [0,3072) x | [3072,4800) Wq|Wk|Wv | [4800,5376) Wo | [5376,5568) bias
__global__ __launch_bounds__(256) void prep_kernel(const float* __restrict__ x,
                                                   const float* __restrict__ Wq,
                                                   const float* __restrict__ Wk,
                                                   const float* __restrict__ Wv,
                                                   const float* __restrict__ Wo,
                                                   const float* __restrict__ bw,
                                                   const float* __restrict__ bf,
                                                   f16* __restrict__ xb,
                                                   f16* __restrict__ wqkv16,
                                                   f16* __restrict__ wo16,
                                                   float* __restrict__ biasTab) {
    int bid = blockIdx.x;
    int t = threadIdx.x;
    if (bid < 5376) {
        const float* src;
        f16* dst;
        float scale = 1.0f;
        int i;
        if (bid < 3072) {            // x: 786432 float4
            i = bid * 256 + t; src = x; dst = xb;
        } else if (bid < 4800) {     // Wq|Wk|Wv: 3 x 147456 float4 -> contiguous wqkv16
            i = (bid - 3072) * 256 + t;
            dst = wqkv16;
            if (i < 147456)      { src = Wq; scale = 0.18033688011112f; }   // (1/8)*log2e
            else if (i < 294912) { src = Wk - 147456 * 4; }
            else                 { src = Wv - 294912 * 4; }
        } else {                     // Wo: 147456 float4
            i = (bid - 4800) * 256 + t; src = Wo; dst = wo16;
        }
        f32x4 v = reinterpret_cast<const f32x4*>(src)[i];
        union { f16 h[4]; unsigned long long u; } o;
        o.h[0] = (f16)(v.x * scale);
        o.h[1] = (f16)(v.y * scale);
        o.h[2] = (f16)(v.z * scale);
        o.h[3] = (f16)(v.w * scale);
        reinterpret_cast<unsigned long long*>(dst)[i] = o.u;
    } else {                         // bias table, log2 domain
        int idx = (bid - 5376) * 256 + t;
        if (idx >= H_ * 4095) return;
        int h = idx / 4095, d = idx % 4095;
        int rel = min(1000, max(-1000, d - 2047));
        int r = rel + 1000;
        float s = 0.f;
#pragma unroll
        for (int tt = 0; tt < NB_; ++tt) s += bf[r * NB_ + tt] * bw[h * NB_ + tt];
        biasTab[h * 4095 + d] = s * 1.44269504088896f;
    }
}

// ---------------- V transpose: vt[(b*H+h)*64 + v][token] = V[b][token][h*64+v] ----------------
__global__ __launch_bounds__(256) void vtrans_kernel(const f16* __restrict__ qkv,
                                                     f16* __restrict__ vt) {
    __shared__ f16 tile[64][72];
    int blk = blockIdx.x;            // (b*H+h)*32 + tb
    int tb = blk & 31;
    int bh = blk >> 5;
    int b = bh / H_;
    int tok0 = tb << 6;
    int t = threadIdx.x;
    const f16* src = qkv + (size_t)b * S_ * QKV_LD + 1536 + (bh - b * H_) * 64;
#pragma unroll
    for (int j = 0; j < 2; ++j) {
        int u = t + (j << 8);
        int r = u >> 3, c = (u & 7) << 3;
        *reinterpret_cast<f16x8*>(&tile[r][c]) =
            *reinterpret_cast<const f16x8*>(src + (size_t)(tok0 + r) * QKV_LD + c);
    }
    __syncthreads();
    f16* dst = vt + (size_t)bh * 64 * S_ + tok0;
#pragma unroll
    for (int j = 0; j < 2; ++j) {
        int u = t + (j << 8);
        int v = u >> 3, tc = (u & 7) << 3;
        union { f16 h8[8]; f16x8 v8; } o;
#pragma unroll
        for (int i = 0; i < 8; ++i) o.h8[i] = tile[tc + i][v];
        *reinterpret_cast<f16x8*>(&dst[(size_t)v * S_ + tc]) = o.v8;
    }
}

// ---------------- NT GEMM via global_load_lds, source-pre-swizzled chunks ----------------
template <typename OutT>
__global__ __launch_bounds__(256) void gemm_nt(const f16* __restrict__ A,
                                               const f16* __restrict__ Bm,
                                               OutT* __restrict__ C,
                                               int M, int N, int K, float alpha) {
    __shared__ __align__(16) f16 As[128 * 32];
    __shared__ __align__(16) f16 Bs[128 * 32];
    const int tiles_n = N >> 7;
    int tm = blockIdx.x / tiles_n, tn = blockIdx.x % tiles_n;
    int m0 = tm << 7, n0 = tn << 7;
    int t = threadIdx.x;
    int w = t >> 6, l = t & 63;
    int wr = w >> 1, wc = w & 1;
    int fr = l & 15, hi = l >> 4;
    f32x4 acc[4][4] = {};

    for (int k0 = 0; k0 < K; k0 += 32) {
#pragma unroll
        for (int j = 0; j < 2; ++j) {
            int u = t + (j << 8);
            int row = u >> 2, ch = u & 3;
            int gcol = k0 + ((ch ^ (row & 3)) << 3);
            gload16(&A[(size_t)(m0 + row) * K + gcol], As + (w << 9) + (j << 11));
            gload16(&Bm[(size_t)(n0 + row) * K + gcol], Bs + (w << 9) + (j << 11));
        }
        __syncthreads();
        f16x8 af[4], bfv[4];
#pragma unroll
        for (int m = 0; m < 4; ++m) {
            int row = wr * 64 + m * 16 + fr;
            af[m] = *reinterpret_cast<const f16x8*>(&As[row * 32 + ((hi ^ (fr & 3)) << 3)]);
        }
#pragma unroll
        for (int n = 0; n < 4; ++n) {
            int row = wc * 64 + n * 16 + fr;
            bfv[n] = *reinterpret_cast<const f16x8*>(&Bs[row * 32 + ((hi ^ (fr & 3)) << 3)]);
        }
#pragma unroll
        for (int m = 0; m < 4; ++m)
#pragma unroll
            for (int n = 0; n < 4; ++n)
                acc[m][n] = __builtin_amdgcn_mfma_f32_16x16x32_f16(af[m], bfv[n], acc[m][n], 0, 0, 0);
        __syncthreads();
    }
    int cc = l & 15, cr = (l >> 4) << 2;
#pragma unroll
    for (int m = 0; m < 4; ++m)
#pragma unroll
        for (int n = 0; n < 4; ++n)
#pragma unroll
            for (int j = 0; j < 4; ++j) {
                int rg = m0 + wr * 64 + m * 16 + cr + j;
                int cg = n0 + wc * 64 + n * 16 + cc;
                C[(size_t)rg * N + cg] = (OutT)(acc[m][n][j] * alpha);
            }
}

// ---------------- attention v7: v5 orientation, NO K/V LDS staging (L2-direct), ----------------
// reg-prefetched K/V, psh double-buffer + raw lgkm barrier (1/tile, vmcnt stays in flight).
// psh read-side XOR swizzle. D mapping: lane(ql)=k/v col, regs=q rows.
#define PSWZ(row) ((((row) >> 2) & 3) << 3)
__global__ __launch_bounds__(256, 3) void attn_kernel(const f16* __restrict__ qp,
                                                      const f16* __restrict__ kp,
                                                      const f16* __restrict__ vt,
                                                      const float* __restrict__ biasTab,
                                                      float* __restrict__ attn_out,
                                                      f16* __restrict__ ctx_out) {
    __shared__ __align__(16) f16 psh[2][64][72];     // 18432 B (double-buffered p tile)
    __shared__ float bias_l[2112];                   // 8448 B
    __shared__ float red_l[64][2];
    __shared__ float li_s[64];

    // XCD-chunked swizzle: 768 = 8 * 96
    int orig = blockIdx.x;
    int blk = (orig & 7) * 96 + (orig >> 3);
    int qt = blk & 31;
    int bh = blk >> 5;
    int h = bh % H_;
    int b = bh / H_;
    int q0 = qt << 6;

    int t = threadIdx.x;
    int w = t >> 6, l = t & 63;
    int wq = w >> 1, wk = w & 1;
    int ql = l & 31;
    int hi = l >> 5;
    int hi4 = hi << 2, hi8 = hi << 3;

    const size_t rowbase = (size_t)b * S_ * QKV_LD + (size_t)h * HS;
    const f16* vbase = vt + (size_t)bh * HS * S_;

    // Q fragments, held whole kernel
    f16x8 qf[4];
    {
        const f16* qrow = qp + rowbase + (size_t)(q0 + wq * 32 + ql) * QKV_LD + hi8;
#pragma unroll
        for (int ci = 0; ci < 4; ++ci) qf[ci] = *reinterpret_cast<const f16x8*>(qrow + ci * 16);
    }

    // stage bias slice: bias_l[i] = biasTab[h][i + 1984 - q0]; i = k - q_local + 63 in [0,2110]
    {
        const float* bt = biasTab + h * 4095 + (1984 - q0);
        for (int i = t; i < 2111; i += 256) bias_l[i] = bt[i];
    }
    __syncthreads();

    // ---------------- pass 1: row sums, barrier-free streaming, prefetched K ----------------
    float lsum[16];
#pragma unroll
    for (int r = 0; r < 16; ++r) lsum[r] = 0.f;

    f16x8 kc0, kc1, kc2, kc3;
    {
        const f16* kr = kp + rowbase + (size_t)(wk * 32 + ql) * QKV_LD + hi8;
        kc0 = *reinterpret_cast<const f16x8*>(kr);
        kc1 = *reinterpret_cast<const f16x8*>(kr + 16);
        kc2 = *reinterpret_cast<const f16x8*>(kr + 32);
        kc3 = *reinterpret_cast<const f16x8*>(kr + 48);
    }
    for (int j = 0; j < 32; ++j) {
        int kt = j * 64 + wk * 32;
        f32x16 s = ZERO16;
        s = __builtin_amdgcn_mfma_f32_32x32x16_f16(qf[0], kc0, s, 0, 0, 0);
        s = __builtin_amdgcn_mfma_f32_32x32x16_f16(qf[1], kc1, s, 0, 0, 0);
        s = __builtin_amdgcn_mfma_f32_32x32x16_f16(qf[2], kc2, s, 0, 0, 0);
        s = __builtin_amdgcn_mfma_f32_32x32x16_f16(qf[3], kc3, s, 0, 0, 0);
        {   // prefetch next slice (wraps to 0 on last iter; harmless)
            int nkt = (j < 31) ? kt + 64 : wk * 32;
            const f16* kr = kp + rowbase + (size_t)(nkt + ql) * QKV_LD + hi8;
            kc0 = *reinterpret_cast<const f16x8*>(kr);
            kc1 = *reinterpret_cast<const f16x8*>(kr + 16);
            kc2 = *reinterpret_cast<const f16x8*>(kr + 32);
            kc3 = *reinterpret_cast<const f16x8*>(kr + 48);
        }
        const float* bl = bias_l + (kt + ql + 63 - wq * 32 - hi4);
#pragma unroll
        for (int r = 0; r < 16; ++r) {
            const int cr = (r & 3) + 8 * (r >> 2);
            lsum[r] += __builtin_amdgcn_exp2f(s[r] + bl[-cr]);
        }
    }

    // reduce: 32 k-lanes via shfl, then across wk via LDS
#pragma unroll
    for (int off = 1; off < 32; off <<= 1) {
#pragma unroll
        for (int r = 0; r < 16; ++r) lsum[r] += __shfl_xor(lsum[r], off);
    }
    if (ql == 0) {
#pragma unroll
        for (int r = 0; r < 16; ++r)
            red_l[wq * 32 + (r & 3) + 8 * (r >> 2) + hi4][wk] = lsum[r];
    }
    __syncthreads();
    if (t < 64) li_s[t] = 1.0f / (red_l[t][0] + red_l[t][1]);
    __syncthreads();
    float lreg[16];
#pragma unroll
    for (int r = 0; r < 16; ++r) lreg[r] = li_s[wq * 32 + (r & 3) + 8 * (r >> 2) + hi4];

    // ---------------- pass 2: recompute, coalesced attn stores, psh-dbuf PV ----------------
    f32x16 oacc = ZERO16;
    float* aout = attn_out + (((size_t)b * H_ + h) * S_ + q0) * S_;
    const int kcol_loc = wk * 32 + ql;      // k (and v) lane column within tile

    f16x8 vc0, vc1, vc2, vc3;
    {
        const f16* kr = kp + rowbase + (size_t)kcol_loc * QKV_LD + hi8;
        kc0 = *reinterpret_cast<const f16x8*>(kr);
        kc1 = *reinterpret_cast<const f16x8*>(kr + 16);
        kc2 = *reinterpret_cast<const f16x8*>(kr + 32);
        kc3 = *reinterpret_cast<const f16x8*>(kr + 48);
        const f16* vr = vbase + (size_t)kcol_loc * S_ + hi8;
        vc0 = *reinterpret_cast<const f16x8*>(vr);
        vc1 = *reinterpret_cast<const f16x8*>(vr + 16);
        vc2 = *reinterpret_cast<const f16x8*>(vr + 32);
        vc3 = *reinterpret_cast<const f16x8*>(vr + 48);
    }

    for (int tix = 0; tix < 32; ++tix) {
        int kb0 = tix << 6;
        int kcol = kb0 + kcol_loc;
        int nkb = (tix < 31) ? kb0 + 64 : 0;
        f32x16 s = ZERO16;
        s = __builtin_amdgcn_mfma_f32_32x32x16_f16(qf[0], kc0, s, 0, 0, 0);
        s = __builtin_amdgcn_mfma_f32_32x32x16_f16(qf[1], kc1, s, 0, 0, 0);
        s = __builtin_amdgcn_mfma_f32_32x32x16_f16(qf[2], kc2, s, 0, 0, 0);
        s = __builtin_amdgcn_mfma_f32_32x32x16_f16(qf[3], kc3, s, 0, 0, 0);
        {   // prefetch next K (kc consumed)
            const f16* kr = kp + rowbase + (size_t)(nkb + kcol_loc) * QKV_LD + hi8;
            kc0 = *reinterpret_cast<const f16x8*>(kr);
            kc1 = *reinterpret_cast<const f16x8*>(kr + 16);
            kc2 = *reinterpret_cast<const f16x8*>(kr + 32);
            kc3 = *reinterpret_cast<const f16x8*>(kr + 48);
        }
        const int buf = tix & 1;
        const float* bl = bias_l + (kcol + 63 - wq * 32 - hi4);
#pragma unroll
        for (int r = 0; r < 16; ++r) {
            const int cr = (r & 3) + 8 * (r >> 2);
            int row = wq * 32 + cr + hi4;
            float p = __builtin_amdgcn_exp2f(s[r] + bl[-cr]) * lreg[r];
            __builtin_nontemporal_store(p, &aout[(size_t)row * S_ + kcol]);
            psh[buf][row][kcol_loc ^ PSWZ(row)] = (f16)p;
        }
        // order psh writes only (lgkm); leave global loads/stores (vmcnt) in flight
        asm volatile("s_waitcnt lgkmcnt(0)" ::: "memory");
        __builtin_amdgcn_s_barrier();
        {
            const int rowq = wq * 32 + ql;
            const int sw = PSWZ(rowq);
            f16x8 pa0 = *reinterpret_cast<const f16x8*>(&psh[buf][rowq][(0  + hi8) ^ sw]);
            f16x8 pa1 = *reinterpret_cast<const f16x8*>(&psh[buf][rowq][(16 + hi8) ^ sw]);
            f16x8 pa2 = *reinterpret_cast<const f16x8*>(&psh[buf][rowq][(32 + hi8) ^ sw]);
            f16x8 pa3 = *reinterpret_cast<const f16x8*>(&psh[buf][rowq][(48 + hi8) ^ sw]);
            oacc = __builtin_amdgcn_mfma_f32_32x32x16_f16(pa0, vc0, oacc, 0, 0, 0);
            oacc = __builtin_amdgcn_mfma_f32_32x32x16_f16(pa1, vc1, oacc, 0, 0, 0);
            oacc = __builtin_amdgcn_mfma_f32_32x32x16_f16(pa2, vc2, oacc, 0, 0, 0);
            oacc = __builtin_amdgcn_mfma_f32_32x32x16_f16(pa3, vc3, oacc, 0, 0, 0);
        }
        {   // prefetch next V (vc consumed)
            const f16* vr = vbase + (size_t)kcol_loc * S_ + nkb + hi8;
            vc0 = *reinterpret_cast<const f16x8*>(vr);
            vc1 = *reinterpret_cast<const f16x8*>(vr + 16);
            vc2 = *reinterpret_cast<const f16x8*>(vr + 32);
            vc3 = *reinterpret_cast<const f16x8*>(vr + 48);
        }
    }

    // ctx write: v = kcol_loc (lane), q rows from regs
    {
        f16* cbase = ctx_out + ((size_t)b * S_ + q0) * DMODEL + h * HS + kcol_loc;
#pragma unroll
        for (int r = 0; r < 16; ++r) {
            int row = wq * 32 + (r & 3) + 8 * (r >> 2) + hi4;
            cbase[(size_t)row * DMODEL] = (f16)oacc[r];
        }
    }
}

// ---------------- launch ----------------
extern "C" void kernel_launch(void* const* d_in, const int* in_sizes, int n_in,
                              void* d_out, int out_size, void* d_ws, size_t ws_size,
                              hipStream_t stream) {
    const float* x     = (const float*)d_in[0];
    const float* Wq    = (const float*)d_in[1];
    const float* Wk    = (const float*)d_in[2];
    const float* Wv    = (const float*)d_in[3];
    const float* Wo    = (const float*)d_in[4];
    const float* bw    = (const float*)d_in[5];
    const float* bfeat = (const float*)d_in[6];

    char* ws = (char*)d_ws;
    f16*   xb      = (f16*)(ws + 0);           // 4096x768      6,291,456 B (reused as vt after QKV GEMM)
    f16*   vt      = (f16*)(ws + 0);           // 24x64x2048    6,291,456 B
    f16*   qkv     = (f16*)(ws + 6291456);     // 4096x2304    18,874,368 B
    f16*   ctx     = (f16*)(ws + 25165824);    // 4096x768      6,291,456 B
    f16*   wqkv16  = (f16*)(ws + 31457280);    // 2304x768      3,538,944 B
    f16*   wo16    = (f16*)(ws + 34996224);    // 768x768       1,179,648 B
    float* biasTab = (float*)(ws + 36175872);  // 12x4095         196,560 B

    float* out0 = (float*)d_out;
    float* attn = out0 + (size_t)B_ * S_ * DMODEL;

    prep_kernel<<<5568, 256, 0, stream>>>(x, Wq, Wk, Wv, Wo, bw, bfeat,
                                          xb, wqkv16, wo16, biasTab);

    gemm_nt<f16><<<32 * 18, 256, 0, stream>>>(xb, wqkv16, qkv, 4096, QKV_LD, 768, 1.0f);

    vtrans_kernel<<<768, 256, 0, stream>>>(qkv, vt);

    attn_kernel<<<B_ * H_ * (S_ / 64), 256, 0, stream>>>(
        qkv + 0, qkv + 768, vt, biasTab, attn, ctx);

    gemm_nt<float><<<32 * 6, 256, 0, stream>>>(ctx, wo16, out0, 4096, DMODEL, 768, 1.0f);
}

// Round 10
// 173.828 us; speedup vs baseline: 1.8854x; 1.2352x over previous
//
#include <hip/hip_runtime.h>

typedef _Float16 f16;
typedef __attribute__((ext_vector_type(4))) _Float16 f16x4;
typedef __attribute__((ext_vector_type(8))) _Float16 f16x8;
typedef __attribute__((ext_vector_type(4))) float f32x4;
typedef __attribute__((ext_vector_type(16))) float f32x16;

#define B_ 2
#define S_ 2048
#define DMODEL 768
#define H_ 12
#define HS 64
#define NB_ 16
#define QKV_LD 2304   // q,k,v concatenated columns

#define ZERO16 {0.f,0.f,0.f,0.f,0.f,0.f,0.f,0.f,0.f,0.f,0.f,0.f,0.f,0.f,0.f,0.f}

// async global->LDS 16B: LDS dest = wave-uniform base + lane*16
__device__ __forceinline__ void gload16(const f16* g, f16* lds) {
    __builtin_amdgcn_global_load_lds((const __attribute__((address_space(1))) void*)g,
                                     (__attribute__((address_space(3))) void*)lds, 16, 0, 0);
}
#define WAIT_VM0_BARRIER()  do { asm volatile("s_waitcnt vmcnt(0)" ::: "memory"); \
                                 __builtin_amdgcn_s_barrier(); } while (0)

// ---------------- fused prep: casts + bias table ----------------
// grid 5568: [0,3072) x | [3072,4800) Wq|Wk|Wv | [4800,5376) Wo | [5376,5568) bias
__global__ __launch_bounds__(256) void prep_kernel(const float* __restrict__ x,
                                                   const float* __restrict__ Wq,
                                                   const float* __restrict__ Wk,
                                                   const float* __restrict__ Wv,
                                                   const float* __restrict__ Wo,
                                                   const float* __restrict__ bw,
                                                   const float* __restrict__ bf,
                                                   f16* __restrict__ xb,
                                                   f16* __restrict__ wqkv16,
                                                   f16* __restrict__ wo16,
                                                   float* __restrict__ biasTab) {
    int bid = blockIdx.x;
    int t = threadIdx.x;
    if (bid < 5376) {
        const float* src;
        f16* dst;
        float scale = 1.0f;
        int i;
        if (bid < 3072) {            // x: 786432 float4
            i = bid * 256 + t; src = x; dst = xb;
        } else if (bid < 4800) {     // Wq|Wk|Wv: 3 x 147456 float4 -> contiguous wqkv16
            i = (bid - 3072) * 256 + t;
            dst = wqkv16;
            if (i < 147456)      { src = Wq; scale = 0.18033688011112f; }   // (1/8)*log2e
            else if (i < 294912) { src = Wk - 147456 * 4; }
            else                 { src = Wv - 294912 * 4; }
        } else {                     // Wo: 147456 float4
            i = (bid - 4800) * 256 + t; src = Wo; dst = wo16;
        }
        f32x4 v = reinterpret_cast<const f32x4*>(src)[i];
        union { f16 h[4]; unsigned long long u; } o;
        o.h[0] = (f16)(v.x * scale);
        o.h[1] = (f16)(v.y * scale);
        o.h[2] = (f16)(v.z * scale);
        o.h[3] = (f16)(v.w * scale);
        reinterpret_cast<unsigned long long*>(dst)[i] = o.u;
    } else {                         // bias table, log2 domain
        int idx = (bid - 5376) * 256 + t;
        if (idx >= H_ * 4095) return;
        int h = idx / 4095, d = idx % 4095;
        int rel = min(1000, max(-1000, d - 2047));
        int r = rel + 1000;
        float s = 0.f;
#pragma unroll
        for (int tt = 0; tt < NB_; ++tt) s += bf[r * NB_ + tt] * bw[h * NB_ + tt];
        biasTab[h * 4095 + d] = s * 1.44269504088896f;
    }
}

// ---------------- V transpose: vt[(b*H+h)*64 + v][token] = V[b][token][h*64+v] ----------------
__global__ __launch_bounds__(256) void vtrans_kernel(const f16* __restrict__ qkv,
                                                     f16* __restrict__ vt) {
    __shared__ f16 tile[64][72];
    int blk = blockIdx.x;            // (b*H+h)*32 + tb
    int tb = blk & 31;
    int bh = blk >> 5;
    int b = bh / H_;
    int tok0 = tb << 6;
    int t = threadIdx.x;
    const f16* src = qkv + (size_t)b * S_ * QKV_LD + 1536 + (bh - b * H_) * 64;
#pragma unroll
    for (int j = 0; j < 2; ++j) {
        int u = t + (j << 8);
        int r = u >> 3, c = (u & 7) << 3;
        *reinterpret_cast<f16x8*>(&tile[r][c]) =
            *reinterpret_cast<const f16x8*>(src + (size_t)(tok0 + r) * QKV_LD + c);
    }
    __syncthreads();
    f16* dst = vt + (size_t)bh * 64 * S_ + tok0;
#pragma unroll
    for (int j = 0; j < 2; ++j) {
        int u = t + (j << 8);
        int v = u >> 3, tc = (u & 7) << 3;
        union { f16 h8[8]; f16x8 v8; } o;
#pragma unroll
        for (int i = 0; i < 8; ++i) o.h8[i] = tile[tc + i][v];
        *reinterpret_cast<f16x8*>(&dst[(size_t)v * S_ + tc]) = o.v8;
    }
}

// ---------------- NT GEMM: dbuf LDS + early staging, ONE barrier per k-step ----------------
template <typename OutT>
__global__ __launch_bounds__(256) void gemm_nt(const f16* __restrict__ A,
                                               const f16* __restrict__ Bm,
                                               OutT* __restrict__ C,
                                               int M, int N, int K, float alpha) {
    __shared__ __align__(16) f16 As[2][128 * 32];
    __shared__ __align__(16) f16 Bs[2][128 * 32];
    const int tiles_n = N >> 7;
    int tm = blockIdx.x / tiles_n, tn = blockIdx.x % tiles_n;
    int m0 = tm << 7, n0 = tn << 7;
    int t = threadIdx.x;
    int w = t >> 6, l = t & 63;
    int wr = w >> 1, wc = w & 1;
    int fr = l & 15, hi = l >> 4;
    f32x4 acc[4][4] = {};

#define GEMM_STAGE(buf, k0)                                                        \
    do {                                                                           \
        _Pragma("unroll")                                                          \
        for (int j = 0; j < 2; ++j) {                                              \
            int u = t + (j << 8);                                                  \
            int row = u >> 2, ch = u & 3;                                          \
            int gcol = (k0) + ((ch ^ (row & 3)) << 3);                             \
            gload16(&A[(size_t)(m0 + row) * K + gcol], As[buf] + (w << 9) + (j << 11)); \
            gload16(&Bm[(size_t)(n0 + row) * K + gcol], Bs[buf] + (w << 9) + (j << 11)); \
        }                                                                          \
    } while (0)

    const int nk = K >> 5;
    GEMM_STAGE(0, 0);
    WAIT_VM0_BARRIER();
    for (int kt = 0; kt < nk; ++kt) {
        int buf = kt & 1;
        if (kt + 1 < nk) GEMM_STAGE(buf ^ 1, (kt + 1) << 5);
        f16x8 af[4], bfv[4];
#pragma unroll
        for (int m = 0; m < 4; ++m) {
            int row = wr * 64 + m * 16 + fr;
            af[m] = *reinterpret_cast<const f16x8*>(&As[buf][row * 32 + ((hi ^ (fr & 3)) << 3)]);
        }
#pragma unroll
        for (int n = 0; n < 4; ++n) {
            int row = wc * 64 + n * 16 + fr;
            bfv[n] = *reinterpret_cast<const f16x8*>(&Bs[buf][row * 32 + ((hi ^ (fr & 3)) << 3)]);
        }
#pragma unroll
        for (int m = 0; m < 4; ++m)
#pragma unroll
            for (int n = 0; n < 4; ++n)
                acc[m][n] = __builtin_amdgcn_mfma_f32_16x16x32_f16(af[m], bfv[n], acc[m][n], 0, 0, 0);
        WAIT_VM0_BARRIER();
    }
#undef GEMM_STAGE
    int cc = l & 15, cr = (l >> 4) << 2;
#pragma unroll
    for (int m = 0; m < 4; ++m)
#pragma unroll
        for (int n = 0; n < 4; ++n)
#pragma unroll
            for (int j = 0; j < 4; ++j) {
                int rg = m0 + wr * 64 + m * 16 + cr + j;
                int cg = n0 + wc * 64 + n * 16 + cc;
                C[(size_t)rg * N + cg] = (OutT)(acc[m][n][j] * alpha);
            }
}

// ---------------- attention v8: v5 structure + dbuf early staging + psh swizzle ----------------
#define PSWZ(row) ((((row) >> 2) & 3) << 3)
__global__ __launch_bounds__(256, 3) void attn_kernel(const f16* __restrict__ qp,
                                                      const f16* __restrict__ kp,
                                                      const f16* __restrict__ vt,
                                                      const float* __restrict__ biasTab,
                                                      float* __restrict__ attn_out,
                                                      f16* __restrict__ ctx_out) {
    __shared__ __align__(16) union {
        f16 ks1[2][128 * 64];                                // pass 1: 32768 B
        struct { f16 ks[2][64 * 64]; f16 vs[2][64 * 64]; } p2;  // pass 2: 32768 B
    } ar;
    __shared__ __align__(16) f16 psh[64][72];                // 9216 B
    __shared__ float bias_l[2112];                           // 8448 B
    __shared__ float red_l[64][2];
    __shared__ float li_s[64];

    // XCD-chunked swizzle: 768 = 8 * 96
    int orig = blockIdx.x;
    int blk = (orig & 7) * 96 + (orig >> 3);
    int qt = blk & 31;
    int bh = blk >> 5;
    int h = bh % H_;
    int b = bh / H_;
    int q0 = qt << 6;

    int t = threadIdx.x;
    int w = t >> 6, l = t & 63;
    int wq = w >> 1, wk = w & 1;
    int col = l & 31;
    int hi = l >> 5;
    int hi4 = hi << 2, hi8 = hi << 3;

    const size_t rowbase = (size_t)b * S_ * QKV_LD + (size_t)h * HS;
    const f16* vbase = vt + (size_t)bh * HS * S_;

    // Q fragments, held whole kernel
    f16x8 qf[4];
    {
        const f16* qrow = qp + rowbase + (size_t)(q0 + wq * 32 + col) * QKV_LD + hi8;
#pragma unroll
        for (int ci = 0; ci < 4; ++ci) qf[ci] = *reinterpret_cast<const f16x8*>(qrow + ci * 16);
    }

    // stage bias slice: bias_l[i] = biasTab[h][i + 1984 - q0]
    {
        const float* bt = biasTab + h * 4095 + (1984 - q0);
        for (int i = t; i < 2111; i += 256) bias_l[i] = bt[i];
    }

// pass-1 staging: 128 k-rows (4 chunks/thread) into ks1[buf]
#define P1_STAGE(buf, kb0)                                                          \
    do {                                                                            \
        _Pragma("unroll")                                                           \
        for (int j = 0; j < 4; ++j) {                                               \
            int u = t + (j << 8);                                                   \
            int row = u >> 3, ch = u & 7;                                           \
            gload16(kp + rowbase + (size_t)((kb0) + row) * QKV_LD + ((ch ^ (row & 7)) << 3), \
                    ar.ks1[buf] + (w << 9) + (j << 11));                            \
        }                                                                           \
    } while (0)

    float lsum[16];
#pragma unroll
    for (int r = 0; r < 16; ++r) lsum[r] = 0.f;

    P1_STAGE(0, 0);
    WAIT_VM0_BARRIER();          // also publishes bias_l
    for (int jt = 0; jt < 16; ++jt) {
        int buf = jt & 1;
        if (jt + 1 < 16) P1_STAGE(buf ^ 1, (jt + 1) << 7);
#pragma unroll
        for (int half = 0; half < 2; ++half) {
            int krow = half * 64 + wk * 32 + col;
            f32x16 s = ZERO16;
#pragma unroll
            for (int ci = 0; ci < 4; ++ci) {
                f16x8 kf = *reinterpret_cast<const f16x8*>(
                    &ar.ks1[buf][krow * 64 + (((ci * 2 + hi) ^ (krow & 7)) << 3)]);
                s = __builtin_amdgcn_mfma_f32_32x32x16_f16(qf[ci], kf, s, 0, 0, 0);
            }
            int kcol = (jt << 7) + krow;
            const float* bl = bias_l + (kcol + 63 - (wq * 32 + hi4));
#pragma unroll
            for (int r = 0; r < 16; ++r) {
                const int cr = (r & 3) + 8 * (r >> 2);
                lsum[r] += __builtin_amdgcn_exp2f(s[r] + bl[-cr]);
            }
        }
        WAIT_VM0_BARRIER();
    }
#undef P1_STAGE

    // reduce sums: 32 lanes (cols) -> LDS merge across wk halves
#pragma unroll
    for (int off = 1; off < 32; off <<= 1) {
#pragma unroll
        for (int r = 0; r < 16; ++r) lsum[r] += __shfl_xor(lsum[r], off);
    }
    if (col == 0) {
#pragma unroll
        for (int r = 0; r < 16; ++r)
            red_l[wq * 32 + (r & 3) + 8 * (r >> 2) + hi4][wk] = lsum[r];
    }
    __syncthreads();
    if (t < 64) li_s[t] = 1.0f / (red_l[t][0] + red_l[t][1]);
    __syncthreads();
    float lreg[16];
#pragma unroll
    for (int r = 0; r < 16; ++r) lreg[r] = li_s[wq * 32 + (r & 3) + 8 * (r >> 2) + hi4];

// pass-2 staging: 64 K rows + 64 V rows into ks/vs[buf]
#define P2_STAGE(buf, kb0)                                                          \
    do {                                                                            \
        _Pragma("unroll")                                                           \
        for (int j = 0; j < 2; ++j) {                                               \
            int u = t + (j << 8);                                                   \
            int row = u >> 3, ch = u & 7;                                           \
            int sw = ((ch ^ (row & 7)) << 3);                                       \
            gload16(kp + rowbase + (size_t)((kb0) + row) * QKV_LD + sw,             \
                    ar.p2.ks[buf] + (w << 9) + (j << 11));                          \
            gload16(vbase + (size_t)row * S_ + (kb0) + sw,                          \
                    ar.p2.vs[buf] + (w << 9) + (j << 11));                          \
        }                                                                           \
    } while (0)

    // ---------------- pass 2: recompute, write attn, PV ----------------
    f32x16 oacc = ZERO16;
    float* aout = attn_out + (((size_t)b * H_ + h) * S_ + q0) * S_;
    const int kcol_loc = wk * 32 + col;

    P2_STAGE(0, 0);
    WAIT_VM0_BARRIER();
    for (int tix = 0; tix < 32; ++tix) {
        int buf = tix & 1;
        int kb0 = tix << 6;
        if (tix + 1 < 32) P2_STAGE(buf ^ 1, kb0 + 64);
        f32x16 s = ZERO16;
#pragma unroll
        for (int ci = 0; ci < 4; ++ci) {
            f16x8 kf = *reinterpret_cast<const f16x8*>(
                &ar.p2.ks[buf][kcol_loc * 64 + (((ci * 2 + hi) ^ (kcol_loc & 7)) << 3)]);
            s = __builtin_amdgcn_mfma_f32_32x32x16_f16(qf[ci], kf, s, 0, 0, 0);
        }
        int kcol = kb0 + kcol_loc;
        const float* bl = bias_l + (kcol + 63 - (wq * 32 + hi4));
#pragma unroll
        for (int r = 0; r < 16; ++r) {
            const int cr = (r & 3) + 8 * (r >> 2);
            int row = wq * 32 + cr + hi4;
            float p = __builtin_amdgcn_exp2f(s[r] + bl[-cr]) * lreg[r];
            __builtin_nontemporal_store(p, &aout[(size_t)row * S_ + kcol]);
            psh[row][kcol_loc ^ PSWZ(row)] = (f16)p;
        }
        // publish psh only (lgkm); keep next-tile staging (vmcnt) in flight
        asm volatile("s_waitcnt lgkmcnt(0)" ::: "memory");
        __builtin_amdgcn_s_barrier();
        __builtin_amdgcn_sched_barrier(0);
        {
            const int rowq = wq * 32 + col;
            const int sw = PSWZ(rowq);
#pragma unroll
            for (int ci = 0; ci < 4; ++ci) {
                f16x8 pa = *reinterpret_cast<const f16x8*>(&psh[rowq][(ci * 16 + hi8) ^ sw]);
                f16x8 vf = *reinterpret_cast<const f16x8*>(
                    &ar.p2.vs[buf][kcol_loc * 64 + (((ci * 2 + hi) ^ (kcol_loc & 7)) << 3)]);
                oacc = __builtin_amdgcn_mfma_f32_32x32x16_f16(pa, vf, oacc, 0, 0, 0);
            }
        }
        __syncthreads();   // psh reads done + next-tile staging landed
    }
#undef P2_STAGE

    // ctx write
    {
        f16* cbase = ctx_out + ((size_t)b * S_ + q0) * DMODEL + h * HS + kcol_loc;
#pragma unroll
        for (int r = 0; r < 16; ++r) {
            int row = wq * 32 + (r & 3) + 8 * (r >> 2) + hi4;
            cbase[(size_t)row * DMODEL] = (f16)oacc[r];
        }
    }
}

// ---------------- launch ----------------
extern "C" void kernel_launch(void* const* d_in, const int* in_sizes, int n_in,
                              void* d_out, int out_size, void* d_ws, size_t ws_size,
                              hipStream_t stream) {
    const float* x     = (const float*)d_in[0];
    const float* Wq    = (const float*)d_in[1];
    const float* Wk    = (const float*)d_in[2];
    const float* Wv    = (const float*)d_in[3];
    const float* Wo    = (const float*)d_in[4];
    const float* bw    = (const float*)d_in[5];
    const float* bfeat = (const float*)d_in[6];

    char* ws = (char*)d_ws;
    f16*   xb      = (f16*)(ws + 0);           // 4096x768      6,291,456 B (reused as vt after QKV GEMM)
    f16*   vt      = (f16*)(ws + 0);           // 24x64x2048    6,291,456 B
    f16*   qkv     = (f16*)(ws + 6291456);     // 4096x2304    18,874,368 B
    f16*   ctx     = (f16*)(ws + 25165824);    // 4096x768      6,291,456 B
    f16*   wqkv16  = (f16*)(ws + 31457280);    // 2304x768      3,538,944 B
    f16*   wo16    = (f16*)(ws + 34996224);    // 768x768       1,179,648 B
    float* biasTab = (float*)(ws + 36175872);  // 12x4095         196,560 B

    float* out0 = (float*)d_out;
    float* attn = out0 + (size_t)B_ * S_ * DMODEL;

    prep_kernel<<<5568, 256, 0, stream>>>(x, Wq, Wk, Wv, Wo, bw, bfeat,
                                          xb, wqkv16, wo16, biasTab);

    gemm_nt<f16><<<32 * 18, 256, 0, stream>>>(xb, wqkv16, qkv, 4096, QKV_LD, 768, 1.0f);

    vtrans_kernel<<<768, 256, 0, stream>>>(qkv, vt);

    attn_kernel<<<B_ * H_ * (S_ / 64), 256, 0, stream>>>(
        qkv + 0, qkv + 768, vt, biasTab, attn, ctx);

    gemm_nt<float><<<32 * 6, 256, 0, stream>>>(ctx, wo16, out0, 4096, DMODEL, 768, 1.0f);
}

// Round 11
// 171.551 us; speedup vs baseline: 1.9105x; 1.0133x over previous
//
#include <hip/hip_runtime.h>

typedef _Float16 f16;
typedef __attribute__((ext_vector_type(4))) _Float16 f16x4;
typedef __attribute__((ext_vector_type(8))) _Float16 f16x8;
typedef __attribute__((ext_vector_type(4))) float f32x4;
typedef __attribute__((ext_vector_type(16))) float f32x16;

#define B_ 2
#define S_ 2048
#define DMODEL 768
#define H_ 12
#define HS 64
#define NB_ 16
#define QKV_LD 2304   // q,k,v concatenated columns

#define ZERO16 {0.f,0.f,0.f,0.f,0.f,0.f,0.f,0.f,0.f,0.f,0.f,0.f,0.f,0.f,0.f,0.f}

// async global->LDS 16B: LDS dest = wave-uniform base + lane*16
__device__ __forceinline__ void gload16(const f16* g, f16* lds) {
    __builtin_amdgcn_global_load_lds((const __attribute__((address_space(1))) void*)g,
                                     (__attribute__((address_space(3))) void*)lds, 16, 0, 0);
}
#define WAIT_VM0_BARRIER()  do { asm volatile("s_waitcnt vmcnt(0) lgkmcnt(0)" ::: "memory"); \
                                 __builtin_amdgcn_s_barrier(); } while (0)

// ---------------- fused prep: casts + bias table ----------------
// grid 5568: [0,3072) x | [3072,4800) Wq|Wk|Wv | [4800,5376) Wo | [5376,5568) bias
__global__ __launch_bounds__(256) void prep_kernel(const float* __restrict__ x,
                                                   const float* __restrict__ Wq,
                                                   const float* __restrict__ Wk,
                                                   const float* __restrict__ Wv,
                                                   const float* __restrict__ Wo,
                                                   const float* __restrict__ bw,
                                                   const float* __restrict__ bf,
                                                   f16* __restrict__ xb,
                                                   f16* __restrict__ wqkv16,
                                                   f16* __restrict__ wo16,
                                                   float* __restrict__ biasTab) {
    int bid = blockIdx.x;
    int t = threadIdx.x;
    if (bid < 5376) {
        const float* src;
        f16* dst;
        float scale = 1.0f;
        int i;
        if (bid < 3072) {            // x: 786432 float4
            i = bid * 256 + t; src = x; dst = xb;
        } else if (bid < 4800) {     // Wq|Wk|Wv: 3 x 147456 float4 -> contiguous wqkv16
            i = (bid - 3072) * 256 + t;
            dst = wqkv16;
            if (i < 147456)      { src = Wq; scale = 0.18033688011112f; }   // (1/8)*log2e
            else if (i < 294912) { src = Wk - 147456 * 4; }
            else                 { src = Wv - 294912 * 4; }
        } else {                     // Wo: 147456 float4
            i = (bid - 4800) * 256 + t; src = Wo; dst = wo16;
        }
        f32x4 v = reinterpret_cast<const f32x4*>(src)[i];
        union { f16 h[4]; unsigned long long u; } o;
        o.h[0] = (f16)(v.x * scale);
        o.h[1] = (f16)(v.y * scale);
        o.h[2] = (f16)(v.z * scale);
        o.h[3] = (f16)(v.w * scale);
        reinterpret_cast<unsigned long long*>(dst)[i] = o.u;
    } else {                         // bias table, log2 domain
        int idx = (bid - 5376) * 256 + t;
        if (idx >= H_ * 4095) return;
        int h = idx / 4095, d = idx % 4095;
        int rel = min(1000, max(-1000, d - 2047));
        int r = rel + 1000;
        float s = 0.f;
#pragma unroll
        for (int tt = 0; tt < NB_; ++tt) s += bf[r * NB_ + tt] * bw[h * NB_ + tt];
        biasTab[h * 4095 + d] = s * 1.44269504088896f;
    }
}

// ---------------- V transpose: vt[(b*H+h)*64 + v][token] = V[b][token][h*64+v] ----------------
__global__ __launch_bounds__(256) void vtrans_kernel(const f16* __restrict__ qkv,
                                                     f16* __restrict__ vt) {
    __shared__ f16 tile[64][72];
    int blk = blockIdx.x;            // (b*H+h)*32 + tb
    int tb = blk & 31;
    int bh = blk >> 5;
    int b = bh / H_;
    int tok0 = tb << 6;
    int t = threadIdx.x;
    const f16* src = qkv + (size_t)b * S_ * QKV_LD + 1536 + (bh - b * H_) * 64;
#pragma unroll
    for (int j = 0; j < 2; ++j) {
        int u = t + (j << 8);
        int r = u >> 3, c = (u & 7) << 3;
        *reinterpret_cast<f16x8*>(&tile[r][c]) =
            *reinterpret_cast<const f16x8*>(src + (size_t)(tok0 + r) * QKV_LD + c);
    }
    __syncthreads();
    f16* dst = vt + (size_t)bh * 64 * S_ + tok0;
#pragma unroll
    for (int j = 0; j < 2; ++j) {
        int u = t + (j << 8);
        int v = u >> 3, tc = (u & 7) << 3;
        union { f16 h8[8]; f16x8 v8; } o;
#pragma unroll
        for (int i = 0; i < 8; ++i) o.h8[i] = tile[tc + i][v];
        *reinterpret_cast<f16x8*>(&dst[(size_t)v * S_ + tc]) = o.v8;
    }
}

// ---------------- NT GEMM: dbuf LDS + early staging, ONE barrier per k-step ----------------
// NT = tile width (128 or 64); tile height fixed 128.
template <typename OutT, int NT>
__global__ __launch_bounds__(256) void gemm_nt(const f16* __restrict__ A,
                                               const f16* __restrict__ Bm,
                                               OutT* __restrict__ C,
                                               int M, int N, int K, float alpha) {
    constexpr int NF  = NT / 32;    // col frags per wave
    constexpr int BCH = NT / 64;    // B staging chunks per thread
    __shared__ __align__(16) f16 As[2][128 * 32];
    __shared__ __align__(16) f16 Bs[2][NT * 32];
    const int tiles_n = N / NT;
    int tm = blockIdx.x / tiles_n, tn = blockIdx.x % tiles_n;
    int m0 = tm << 7, n0 = tn * NT;
    int t = threadIdx.x;
    int w = t >> 6, l = t & 63;
    int wr = w >> 1, wc = w & 1;
    int fr = l & 15, hi = l >> 4;
    f32x4 acc[4][NF] = {};

#define GEMM_STAGE(buf, k0)                                                        \
    do {                                                                           \
        _Pragma("unroll")                                                          \
        for (int j = 0; j < 2; ++j) {                                              \
            int u = t + (j << 8);                                                  \
            int row = u >> 2, ch = u & 3;                                          \
            int gcol = (k0) + ((ch ^ (row & 3)) << 3);                             \
            gload16(&A[(size_t)(m0 + row) * K + gcol], As[buf] + (w << 9) + (j << 11)); \
        }                                                                          \
        _Pragma("unroll")                                                          \
        for (int j = 0; j < BCH; ++j) {                                            \
            int u = t + (j << 8);                                                  \
            int row = u >> 2, ch = u & 3;                                          \
            int gcol = (k0) + ((ch ^ (row & 3)) << 3);                             \
            gload16(&Bm[(size_t)(n0 + row) * K + gcol], Bs[buf] + (w << 9) + (j << 11)); \
        }                                                                          \
    } while (0)

    const int nk = K >> 5;
    GEMM_STAGE(0, 0);
    WAIT_VM0_BARRIER();
    for (int kt = 0; kt < nk; ++kt) {
        int buf = kt & 1;
        if (kt + 1 < nk) GEMM_STAGE(buf ^ 1, (kt + 1) << 5);
        f16x8 af[4], bfv[NF];
#pragma unroll
        for (int m = 0; m < 4; ++m) {
            int row = wr * 64 + m * 16 + fr;
            af[m] = *reinterpret_cast<const f16x8*>(&As[buf][row * 32 + ((hi ^ (fr & 3)) << 3)]);
        }
#pragma unroll
        for (int n = 0; n < NF; ++n) {
            int row = wc * (NT / 2) + n * 16 + fr;
            bfv[n] = *reinterpret_cast<const f16x8*>(&Bs[buf][row * 32 + ((hi ^ (fr & 3)) << 3)]);
        }
#pragma unroll
        for (int m = 0; m < 4; ++m)
#pragma unroll
            for (int n = 0; n < NF; ++n)
                acc[m][n] = __builtin_amdgcn_mfma_f32_16x16x32_f16(af[m], bfv[n], acc[m][n], 0, 0, 0);
        WAIT_VM0_BARRIER();
    }
#undef GEMM_STAGE
    int cc = l & 15, cr = (l >> 4) << 2;
#pragma unroll
    for (int m = 0; m < 4; ++m)
#pragma unroll
        for (int n = 0; n < NF; ++n)
#pragma unroll
            for (int j = 0; j < 4; ++j) {
                int rg = m0 + wr * 64 + m * 16 + cr + j;
                int cg = n0 + wc * (NT / 2) + n * 16 + cc;
                C[(size_t)rg * N + cg] = (OutT)(acc[m][n][j] * alpha);
            }
}

// ---------------- attention v9: dbuf staging + DEFERRED attn stores ----------------
// Pass-2 per tile: stage(t+1) -> QK -> softmax (p kept in regs, psh write) -> lgkm barrier
// -> PV -> vmcnt(0)+barrier (staging & last tile's stores had a full tile to retire)
// -> issue this tile's 16 nt stores from regs.
#define PSWZ(row) ((((row) >> 2) & 3) << 3)
__global__ __launch_bounds__(256, 3) void attn_kernel(const f16* __restrict__ qp,
                                                      const f16* __restrict__ kp,
                                                      const f16* __restrict__ vt,
                                                      const float* __restrict__ biasTab,
                                                      float* __restrict__ attn_out,
                                                      f16* __restrict__ ctx_out) {
    __shared__ __align__(16) union {
        f16 ks1[2][128 * 64];                                // pass 1: 32768 B
        struct { f16 ks[2][64 * 64]; f16 vs[2][64 * 64]; } p2;  // pass 2: 32768 B
    } ar;
    __shared__ __align__(16) f16 psh[64][72];                // 9216 B
    __shared__ float bias_l[2112];                           // 8448 B
    __shared__ float red_l[64][2];
    __shared__ float li_s[64];

    // XCD-chunked swizzle: 768 = 8 * 96
    int orig = blockIdx.x;
    int blk = (orig & 7) * 96 + (orig >> 3);
    int qt = blk & 31;
    int bh = blk >> 5;
    int h = bh % H_;
    int b = bh / H_;
    int q0 = qt << 6;

    int t = threadIdx.x;
    int w = t >> 6, l = t & 63;
    int wq = w >> 1, wk = w & 1;
    int col = l & 31;
    int hi = l >> 5;
    int hi4 = hi << 2, hi8 = hi << 3;

    const size_t rowbase = (size_t)b * S_ * QKV_LD + (size_t)h * HS;
    const f16* vbase = vt + (size_t)bh * HS * S_;

    // Q fragments, held whole kernel
    f16x8 qf[4];
    {
        const f16* qrow = qp + rowbase + (size_t)(q0 + wq * 32 + col) * QKV_LD + hi8;
#pragma unroll
        for (int ci = 0; ci < 4; ++ci) qf[ci] = *reinterpret_cast<const f16x8*>(qrow + ci * 16);
    }

    // stage bias slice: bias_l[i] = biasTab[h][i + 1984 - q0]
    {
        const float* bt = biasTab + h * 4095 + (1984 - q0);
        for (int i = t; i < 2111; i += 256) bias_l[i] = bt[i];
    }

// pass-1 staging: 128 k-rows (4 chunks/thread) into ks1[buf]
#define P1_STAGE(buf, kb0)                                                          \
    do {                                                                            \
        _Pragma("unroll")                                                           \
        for (int j = 0; j < 4; ++j) {                                               \
            int u = t + (j << 8);                                                   \
            int row = u >> 3, ch = u & 7;                                           \
            gload16(kp + rowbase + (size_t)((kb0) + row) * QKV_LD + ((ch ^ (row & 7)) << 3), \
                    ar.ks1[buf] + (w << 9) + (j << 11));                            \
        }                                                                           \
    } while (0)

    float lsum[16];
#pragma unroll
    for (int r = 0; r < 16; ++r) lsum[r] = 0.f;

    P1_STAGE(0, 0);
    WAIT_VM0_BARRIER();          // also publishes bias_l
    for (int jt = 0; jt < 16; ++jt) {
        int buf = jt & 1;
        if (jt + 1 < 16) P1_STAGE(buf ^ 1, (jt + 1) << 7);
#pragma unroll
        for (int half = 0; half < 2; ++half) {
            int krow = half * 64 + wk * 32 + col;
            f32x16 s = ZERO16;
#pragma unroll
            for (int ci = 0; ci < 4; ++ci) {
                f16x8 kf = *reinterpret_cast<const f16x8*>(
                    &ar.ks1[buf][krow * 64 + (((ci * 2 + hi) ^ (krow & 7)) << 3)]);
                s = __builtin_amdgcn_mfma_f32_32x32x16_f16(qf[ci], kf, s, 0, 0, 0);
            }
            int kcol = (jt << 7) + krow;
            const float* bl = bias_l + (kcol + 63 - (wq * 32 + hi4));
#pragma unroll
            for (int r = 0; r < 16; ++r) {
                const int cr = (r & 3) + 8 * (r >> 2);
                lsum[r] += __builtin_amdgcn_exp2f(s[r] + bl[-cr]);
            }
        }
        WAIT_VM0_BARRIER();
    }
#undef P1_STAGE

    // reduce sums: 32 lanes (cols) -> LDS merge across wk halves
#pragma unroll
    for (int off = 1; off < 32; off <<= 1) {
#pragma unroll
        for (int r = 0; r < 16; ++r) lsum[r] += __shfl_xor(lsum[r], off);
    }
    if (col == 0) {
#pragma unroll
        for (int r = 0; r < 16; ++r)
            red_l[wq * 32 + (r & 3) + 8 * (r >> 2) + hi4][wk] = lsum[r];
    }
    __syncthreads();
    if (t < 64) li_s[t] = 1.0f / (red_l[t][0] + red_l[t][1]);
    __syncthreads();
    float lreg[16];
#pragma unroll
    for (int r = 0; r < 16; ++r) lreg[r] = li_s[wq * 32 + (r & 3) + 8 * (r >> 2) + hi4];

// pass-2 staging: 64 K rows + 64 V rows into ks/vs[buf]
#define P2_STAGE(buf, kb0)                                                          \
    do {                                                                            \
        _Pragma("unroll")                                                           \
        for (int j = 0; j < 2; ++j) {                                               \
            int u = t + (j << 8);                                                   \
            int row = u >> 3, ch = u & 7;                                           \
            int sw = ((ch ^ (row & 7)) << 3);                                       \
            gload16(kp + rowbase + (size_t)((kb0) + row) * QKV_LD + sw,             \
                    ar.p2.ks[buf] + (w << 9) + (j << 11));                          \
            gload16(vbase + (size_t)row * S_ + (kb0) + sw,                          \
                    ar.p2.vs[buf] + (w << 9) + (j << 11));                          \
        }                                                                           \
    } while (0)

    // ---------------- pass 2 ----------------
    f32x16 oacc = ZERO16;
    float* aout = attn_out + (((size_t)b * H_ + h) * S_ + q0) * S_;
    const int kcol_loc = wk * 32 + col;

    P2_STAGE(0, 0);
    WAIT_VM0_BARRIER();
    float pstash[16];
    for (int tix = 0; tix < 32; ++tix) {
        int buf = tix & 1;
        int kb0 = tix << 6;
        if (tix + 1 < 32) P2_STAGE(buf ^ 1, kb0 + 64);
        __builtin_amdgcn_sched_barrier(0);
        f32x16 s = ZERO16;
#pragma unroll
        for (int ci = 0; ci < 4; ++ci) {
            f16x8 kf = *reinterpret_cast<const f16x8*>(
                &ar.p2.ks[buf][kcol_loc * 64 + (((ci * 2 + hi) ^ (kcol_loc & 7)) << 3)]);
            s = __builtin_amdgcn_mfma_f32_32x32x16_f16(qf[ci], kf, s, 0, 0, 0);
        }
        int kcol = kb0 + kcol_loc;
        const float* bl = bias_l + (kcol + 63 - (wq * 32 + hi4));
#pragma unroll
        for (int r = 0; r < 16; ++r) {
            const int cr = (r & 3) + 8 * (r >> 2);
            int row = wq * 32 + cr + hi4;
            float p = __builtin_amdgcn_exp2f(s[r] + bl[-cr]) * lreg[r];
            pstash[r] = p;
            psh[row][kcol_loc ^ PSWZ(row)] = (f16)p;
        }
        // publish psh only (lgkm); staging + old stores stay in flight
        asm volatile("s_waitcnt lgkmcnt(0)" ::: "memory");
        __builtin_amdgcn_s_barrier();
        __builtin_amdgcn_sched_barrier(0);
        {
            const int rowq = wq * 32 + col;
            const int sw = PSWZ(rowq);
#pragma unroll
            for (int ci = 0; ci < 4; ++ci) {
                f16x8 pa = *reinterpret_cast<const f16x8*>(&psh[rowq][(ci * 16 + hi8) ^ sw]);
                f16x8 vf = *reinterpret_cast<const f16x8*>(
                    &ar.p2.vs[buf][kcol_loc * 64 + (((ci * 2 + hi) ^ (kcol_loc & 7)) << 3)]);
                oacc = __builtin_amdgcn_mfma_f32_32x32x16_f16(pa, vf, oacc, 0, 0, 0);
            }
        }
        // staging(t+1) and stores(t-1) have had a full tile to retire
        asm volatile("s_waitcnt vmcnt(0)" ::: "memory");
        __builtin_amdgcn_s_barrier();
        // now issue this tile's attn stores from registers
#pragma unroll
        for (int r = 0; r < 16; ++r) {
            const int cr = (r & 3) + 8 * (r >> 2);
            int row = wq * 32 + cr + hi4;
            __builtin_nontemporal_store(pstash[r], &aout[(size_t)row * S_ + kcol]);
        }
    }
#undef P2_STAGE

    // ctx write
    {
        f16* cbase = ctx_out + ((size_t)b * S_ + q0) * DMODEL + h * HS + kcol_loc;
#pragma unroll
        for (int r = 0; r < 16; ++r) {
            int row = wq * 32 + (r & 3) + 8 * (r >> 2) + hi4;
            cbase[(size_t)row * DMODEL] = (f16)oacc[r];
        }
    }
}

// ---------------- launch ----------------
extern "C" void kernel_launch(void* const* d_in, const int* in_sizes, int n_in,
                              void* d_out, int out_size, void* d_ws, size_t ws_size,
                              hipStream_t stream) {
    const float* x     = (const float*)d_in[0];
    const float* Wq    = (const float*)d_in[1];
    const float* Wk    = (const float*)d_in[2];
    const float* Wv    = (const float*)d_in[3];
    const float* Wo    = (const float*)d_in[4];
    const float* bw    = (const float*)d_in[5];
    const float* bfeat = (const float*)d_in[6];

    char* ws = (char*)d_ws;
    f16*   xb      = (f16*)(ws + 0);           // 4096x768      6,291,456 B (reused as vt after QKV GEMM)
    f16*   vt      = (f16*)(ws + 0);           // 24x64x2048    6,291,456 B
    f16*   qkv     = (f16*)(ws + 6291456);     // 4096x2304    18,874,368 B
    f16*   ctx     = (f16*)(ws + 25165824);    // 4096x768      6,291,456 B
    f16*   wqkv16  = (f16*)(ws + 31457280);    // 2304x768      3,538,944 B
    f16*   wo16    = (f16*)(ws + 34996224);    // 768x768       1,179,648 B
    float* biasTab = (float*)(ws + 36175872);  // 12x4095         196,560 B

    float* out0 = (float*)d_out;
    float* attn = out0 + (size_t)B_ * S_ * DMODEL;

    prep_kernel<<<5568, 256, 0, stream>>>(x, Wq, Wk, Wv, Wo, bw, bfeat,
                                          xb, wqkv16, wo16, biasTab);

    gemm_nt<f16, 128><<<32 * 18, 256, 0, stream>>>(xb, wqkv16, qkv, 4096, QKV_LD, 768, 1.0f);

    vtrans_kernel<<<768, 256, 0, stream>>>(qkv, vt);

    attn_kernel<<<B_ * H_ * (S_ / 64), 256, 0, stream>>>(
        qkv + 0, qkv + 768, vt, biasTab, attn, ctx);

    gemm_nt<float, 64><<<32 * 12, 256, 0, stream>>>(ctx, wo16, out0, 4096, DMODEL, 768, 1.0f);
}